// Round 1
// baseline (590.978 us; speedup 1.0000x reference)
//
#include <hip/hip_runtime.h>

typedef _Float16 half8 __attribute__((ext_vector_type(8)));
typedef float floatx4 __attribute__((ext_vector_type(4)));

#define MFMA16(a,b,c) __builtin_amdgcn_mfma_f32_16x16x32_f16((a),(b),(c),0,0,0)

// Problem constants
// B=8, Cin=768, H=W=64, N=4096, NT=32768, MID=256, INTER=128, OUT=20

// ---------------------------------------------------------------------------
// Prep: fp32->fp16 weight conversion + fold W/BN/out into Acat[32][384], c0[32]
// out[u][n] = sum_c Acat[u][c]*y[c][n] + sum_o Acat[u][128+o]*x1p[o][n] + c0[u]
// ---------------------------------------------------------------------------
__global__ __launch_bounds__(256) void k_prep(
    const float* __restrict__ w_conv, const float* __restrict__ w_theta,
    const float* __restrict__ w_phi, const float* __restrict__ w_g,
    const float* __restrict__ w_W, const float* __restrict__ b_W,
    const float* __restrict__ gamma, const float* __restrict__ beta,
    const float* __restrict__ mean, const float* __restrict__ var,
    const float* __restrict__ w_out, const float* __restrict__ b_out,
    _Float16* __restrict__ w_conv_h, _Float16* __restrict__ w_theta_h,
    _Float16* __restrict__ w_phi_h, _Float16* __restrict__ w_g_h,
    _Float16* __restrict__ Acat, float* __restrict__ c0)
{
    int tid = blockIdx.x * 256 + threadIdx.x;
    int nth = gridDim.x * 256;
    for (int i = tid; i < 256 * 768; i += nth) w_conv_h[i] = (_Float16)w_conv[i];
    for (int i = tid; i < 128 * 256; i += nth) {
        w_theta_h[i] = (_Float16)w_theta[i];
        w_phi_h[i]   = (_Float16)w_phi[i];
        w_g_h[i]     = (_Float16)w_g[i];
    }
    for (int i = tid; i < 32 * 384; i += nth) {
        int u = i / 384, k = i % 384;
        float v = 0.f;
        if (u < 20) {
            if (k < 128) {
                for (int o = 0; o < 256; ++o) {
                    float inv = gamma[o] * rsqrtf(var[o] + 1e-5f);
                    v += w_out[u * 256 + o] * inv * w_W[o * 128 + k];
                }
            } else {
                v = w_out[u * 256 + (k - 128)];
            }
        }
        Acat[i] = (_Float16)v;
    }
    for (int i = tid; i < 32; i += nth) {
        float v = 0.f;
        if (i < 20) {
            v = b_out[i];
            for (int o = 0; o < 256; ++o) {
                float inv = gamma[o] * rsqrtf(var[o] + 1e-5f);
                float cv = b_W[o] * inv + beta[o] - mean[o] * inv;
                v += w_out[i * 256 + o] * cv;
            }
        }
        c0[i] = v;
    }
}

// ---------------------------------------------------------------------------
// Transpose + convert: x [b][768][4096] fp32 -> xt [(b*4096+n)][768] fp16
// grid (64 n-tiles, 12 c-tiles, 16 = input*8+batch), block 256
// ---------------------------------------------------------------------------
__global__ __launch_bounds__(256) void k_transpose(
    const float* __restrict__ x1, const float* __restrict__ x2,
    _Float16* __restrict__ x1t, _Float16* __restrict__ x2t)
{
    int z = blockIdx.z >> 3, b = blockIdx.z & 7;
    const float* X = (z ? x2 : x1) + (size_t)b * 768 * 4096;
    _Float16* XT = (z ? x2t : x1t) + (size_t)b * 4096 * 768;
    int n0 = blockIdx.x * 64, c0 = blockIdx.y * 64;
    __shared__ float tile[64][68];
    int t = threadIdx.x;
    {
        int c = t >> 2, ns = (t & 3) * 16;
        const float* src = X + (size_t)(c0 + c) * 4096 + n0 + ns;
#pragma unroll
        for (int e = 0; e < 4; ++e)
            *(float4*)&tile[c][ns + e * 4] = *(const float4*)(src + e * 4);
    }
    __syncthreads();
    {
        int n = t >> 2, cs = (t & 3) * 16;
        _Float16 outv[16];
#pragma unroll
        for (int e = 0; e < 16; ++e) outv[e] = (_Float16)tile[cs + e][n];
        _Float16* dst = XT + (size_t)(n0 + n) * 768 + c0 + cs;
        *(half8*)(dst)     = *(half8*)&outv[0];
        *(half8*)(dst + 8) = *(half8*)&outv[8];
    }
}

// ---------------------------------------------------------------------------
// Shared NT GEMM: C[m][n] = sum_k A[m][k]*B[n][k], fp16 in / fp16 out, f32 acc
// A rows dense (lda=K), B rows dense (ldb=K). Tile 128x128, BK=32.
// grid (M/128, N/128), block 256 (4 waves, each 64x64 as 4x4 of 16x16).
// ---------------------------------------------------------------------------
__global__ __launch_bounds__(256) void k_gemm_nt(
    const _Float16* __restrict__ A, const _Float16* __restrict__ B,
    _Float16* __restrict__ C, int K, int ldc)
{
    int m0 = blockIdx.x * 128, n0 = blockIdx.y * 128;
    __shared__ _Float16 As[128][72];
    __shared__ _Float16 Bs[128][72];
    int t = threadIdx.x, wave = t >> 6, lane = t & 63;
    int wm = (wave >> 1) * 64, wn = (wave & 1) * 64;
    int fl = lane & 15, fq = lane >> 4;
    int sr = t >> 2, sc = (t & 3) * 8;

    floatx4 acc[4][4];
#pragma unroll
    for (int i = 0; i < 4; ++i)
#pragma unroll
        for (int j = 0; j < 4; ++j) acc[i][j] = (floatx4){0.f, 0.f, 0.f, 0.f};

    for (int ko = 0; ko < K; ko += 32) {
        __syncthreads();
        half8 av0 = *(const half8*)(A + (size_t)(m0 + sr) * K + ko + sc);
        half8 av1 = *(const half8*)(A + (size_t)(m0 + sr + 64) * K + ko + sc);
        half8 bv0 = *(const half8*)(B + (size_t)(n0 + sr) * K + ko + sc);
        half8 bv1 = *(const half8*)(B + (size_t)(n0 + sr + 64) * K + ko + sc);
        *(half8*)&As[sr][sc] = av0;
        *(half8*)&As[sr + 64][sc] = av1;
        *(half8*)&Bs[sr][sc] = bv0;
        *(half8*)&Bs[sr + 64][sc] = bv1;
        __syncthreads();
        half8 af[4], bf[4];
#pragma unroll
        for (int i = 0; i < 4; ++i) af[i] = *(const half8*)&As[wm + 16 * i + fl][8 * fq];
#pragma unroll
        for (int j = 0; j < 4; ++j) bf[j] = *(const half8*)&Bs[wn + 16 * j + fl][8 * fq];
#pragma unroll
        for (int i = 0; i < 4; ++i)
#pragma unroll
            for (int j = 0; j < 4; ++j) acc[i][j] = MFMA16(af[i], bf[j], acc[i][j]);
    }
#pragma unroll
    for (int i = 0; i < 4; ++i)
#pragma unroll
        for (int j = 0; j < 4; ++j) {
            int row = m0 + wm + 16 * i + 4 * fq;
            int col = n0 + wn + 16 * j + fl;
#pragma unroll
            for (int r = 0; r < 4; ++r)
                C[(size_t)(row + r) * ldc + col] = (_Float16)acc[i][j][r];
        }
}

// ---------------------------------------------------------------------------
// Flash attention (no scale): per block: one batch b, 64 Q-rows.
// theta_t/phi_t: [(b*4096+n)][128] fp16 rows; g: [128][32768]; y_t out: [(b*4096+i)][128]
// 4 waves x 16 i-rows each; j streamed in chunks of 64.
// ---------------------------------------------------------------------------
__global__ __launch_bounds__(256) void k_attn(
    const _Float16* __restrict__ theta_t, const _Float16* __restrict__ phi_t,
    const _Float16* __restrict__ g, _Float16* __restrict__ y_t)
{
    int bi = blockIdx.x;
    int b = bi & 7, it = bi >> 3;   // batch<->XCD affinity swizzle
    int i0g = b * 4096 + it * 64;
    __shared__ _Float16 Qs[64][136];
    __shared__ _Float16 Ks[64][136];
    __shared__ _Float16 Gs[128][72];
    __shared__ _Float16 Ps[64][72];
    int t = threadIdx.x, wave = t >> 6, lane = t & 63;
    int fl = lane & 15, fq = lane >> 4;
    int iw = wave * 16;

    {   // stage Q tile once: [64 i][128 c]
        int i = t >> 2, cs = (t & 3) * 32;
        const _Float16* src = theta_t + (size_t)(i0g + i) * 128 + cs;
#pragma unroll
        for (int e = 0; e < 4; ++e)
            *(half8*)&Qs[i][cs + 8 * e] = *(const half8*)(src + 8 * e);
    }

    floatx4 O[8];
#pragma unroll
    for (int c = 0; c < 8; ++c) O[c] = (floatx4){0.f, 0.f, 0.f, 0.f};
    float mrow[4], lrow[4];
#pragma unroll
    for (int r = 0; r < 4; ++r) { mrow[r] = -1e30f; lrow[r] = 0.f; }

    for (int jc = 0; jc < 64; ++jc) {
        int j0g = b * 4096 + jc * 64;
        __syncthreads();
        {   // stage K chunk: [64 j][128 c]
            int j = t >> 2, cs = (t & 3) * 32;
            const _Float16* src = phi_t + (size_t)(j0g + j) * 128 + cs;
#pragma unroll
            for (int e = 0; e < 4; ++e)
                *(half8*)&Ks[j][cs + 8 * e] = *(const half8*)(src + 8 * e);
        }
        {   // stage V chunk: [128 c][64 j]
            int c = t >> 1, js = (t & 1) * 32;
            const _Float16* src = g + (size_t)c * 32768 + j0g + js;
#pragma unroll
            for (int e = 0; e < 4; ++e)
                *(half8*)&Gs[c][js + 8 * e] = *(const half8*)(src + 8 * e);
        }
        __syncthreads();

        // S[i][j] = sum_c Q[i][c]*K[j][c]   (wave: 16 i x 64 j)
        floatx4 S4[4];
#pragma unroll
        for (int jt = 0; jt < 4; ++jt) S4[jt] = (floatx4){0.f, 0.f, 0.f, 0.f};
#pragma unroll
        for (int kc = 0; kc < 4; ++kc) {
            half8 aq = *(const half8*)&Qs[iw + fl][kc * 32 + 8 * fq];
#pragma unroll
            for (int jt = 0; jt < 4; ++jt) {
                half8 bk = *(const half8*)&Ks[jt * 16 + fl][kc * 32 + 8 * fq];
                S4[jt] = MFMA16(aq, bk, S4[jt]);
            }
        }

        // online softmax; lane holds rows i = 4*fq + r, cols jt*16 + fl
        float rmax[4];
#pragma unroll
        for (int r = 0; r < 4; ++r) rmax[r] = S4[0][r];
#pragma unroll
        for (int jt = 1; jt < 4; ++jt)
#pragma unroll
            for (int r = 0; r < 4; ++r) rmax[r] = fmaxf(rmax[r], S4[jt][r]);
#pragma unroll
        for (int d = 1; d < 16; d <<= 1)
#pragma unroll
            for (int r = 0; r < 4; ++r) rmax[r] = fmaxf(rmax[r], __shfl_xor(rmax[r], d, 64));
        float mnew[4], alpha[4], rsum[4];
#pragma unroll
        for (int r = 0; r < 4; ++r) {
            mnew[r] = fmaxf(mrow[r], rmax[r]);
            alpha[r] = __expf(mrow[r] - mnew[r]);
            mrow[r] = mnew[r];
            rsum[r] = 0.f;
        }
#pragma unroll
        for (int jt = 0; jt < 4; ++jt) {
#pragma unroll
            for (int r = 0; r < 4; ++r) {
                float p = __expf(S4[jt][r] - mnew[r]);
                rsum[r] += p;
                Ps[iw + 4 * fq + r][jt * 16 + fl] = (_Float16)p;
            }
        }
#pragma unroll
        for (int d = 1; d < 16; d <<= 1)
#pragma unroll
            for (int r = 0; r < 4; ++r) rsum[r] += __shfl_xor(rsum[r], d, 64);
#pragma unroll
        for (int r = 0; r < 4; ++r) lrow[r] = lrow[r] * alpha[r] + rsum[r];

        // rescale O (rows of D = 4*fq + r, same per-lane rows as softmax state)
#pragma unroll
        for (int c = 0; c < 8; ++c)
#pragma unroll
            for (int r = 0; r < 4; ++r) O[c][r] *= alpha[r];

        // O[i][c] += sum_j P[i][j] * g[c][j]  (A = Ps rows, B = Gs rows as [n=c][k=j])
#pragma unroll
        for (int kj = 0; kj < 2; ++kj) {
            half8 ap = *(const half8*)&Ps[iw + fl][kj * 32 + 8 * fq];
#pragma unroll
            for (int ct = 0; ct < 8; ++ct) {
                half8 bg = *(const half8*)&Gs[ct * 16 + fl][kj * 32 + 8 * fq];
                O[ct] = MFMA16(ap, bg, O[ct]);
            }
        }
    }

    float linv[4];
#pragma unroll
    for (int r = 0; r < 4; ++r) linv[r] = 1.f / lrow[r];
#pragma unroll
    for (int ct = 0; ct < 8; ++ct)
#pragma unroll
        for (int r = 0; r < 4; ++r)
            y_t[(size_t)(i0g + iw + 4 * fq + r) * 128 + ct * 16 + fl] =
                (_Float16)(O[ct][r] * linv[r]);
}

// ---------------------------------------------------------------------------
// Epilogue GEMM: out[u][nglob] = sum_k Acat[u][k]*Bcat[nglob][k] + c0[u]
// Bcat rows = concat(y_t row (128), x1p_t row (256)). M=32 (20 valid), K=384.
// grid 256 (n-tiles of 128), block 256 (4 waves, each 32m x 32n).
// ---------------------------------------------------------------------------
__global__ __launch_bounds__(256) void k_out(
    const _Float16* __restrict__ y_t, const _Float16* __restrict__ x1p_t,
    const _Float16* __restrict__ Acat, const float* __restrict__ c0,
    float* __restrict__ out)
{
    int n0 = blockIdx.x * 128;
    __shared__ _Float16 As[32][72];
    __shared__ _Float16 Bs[128][72];
    __shared__ float c0s[32];
    int t = threadIdx.x, wave = t >> 6, lane = t & 63;
    int fl = lane & 15, fq = lane >> 4;
    int wn = wave * 32;
    if (t < 32) c0s[t] = c0[t];

    floatx4 acc[2][2];
#pragma unroll
    for (int i = 0; i < 2; ++i)
#pragma unroll
        for (int j = 0; j < 2; ++j) acc[i][j] = (floatx4){0.f, 0.f, 0.f, 0.f};

    for (int ko = 0; ko < 12; ++ko) {
        int kg = ko * 32;
        __syncthreads();
        {
            int n = t >> 1, ks = (t & 1) * 16;
            const _Float16* src = (kg < 128)
                ? y_t + (size_t)(n0 + n) * 128 + kg + ks
                : x1p_t + (size_t)(n0 + n) * 256 + (kg - 128) + ks;
            *(half8*)&Bs[n][ks]     = *(const half8*)src;
            *(half8*)&Bs[n][ks + 8] = *(const half8*)(src + 8);
        }
        if (t < 128) {
            int m = t >> 2, ks = (t & 3) * 8;
            *(half8*)&As[m][ks] = *(const half8*)(Acat + m * 384 + kg + ks);
        }
        __syncthreads();
        half8 af[2], bf[2];
#pragma unroll
        for (int mt = 0; mt < 2; ++mt) af[mt] = *(const half8*)&As[16 * mt + fl][8 * fq];
#pragma unroll
        for (int nt = 0; nt < 2; ++nt) bf[nt] = *(const half8*)&Bs[wn + 16 * nt + fl][8 * fq];
#pragma unroll
        for (int mt = 0; mt < 2; ++mt)
#pragma unroll
            for (int nt = 0; nt < 2; ++nt) acc[mt][nt] = MFMA16(af[mt], bf[nt], acc[mt][nt]);
    }
#pragma unroll
    for (int mt = 0; mt < 2; ++mt)
#pragma unroll
        for (int nt = 0; nt < 2; ++nt)
#pragma unroll
            for (int r = 0; r < 4; ++r) {
                int u = 16 * mt + 4 * fq + r;
                if (u < 20) {
                    int ng = n0 + wn + 16 * nt + fl;
                    int b = ng >> 12, n = ng & 4095;
                    out[((size_t)b * 20 + u) * 4096 + n] = acc[mt][nt][r] + c0s[u];
                }
            }
}

// ---------------------------------------------------------------------------
extern "C" void kernel_launch(void* const* d_in, const int* in_sizes, int n_in,
                              void* d_out, int out_size, void* d_ws, size_t ws_size,
                              hipStream_t stream)
{
    const float* x1     = (const float*)d_in[0];
    const float* x2     = (const float*)d_in[1];
    const float* w_conv = (const float*)d_in[2];
    const float* w_theta= (const float*)d_in[3];
    const float* w_phi  = (const float*)d_in[4];
    const float* w_g    = (const float*)d_in[5];
    const float* w_W    = (const float*)d_in[6];
    const float* b_W    = (const float*)d_in[7];
    const float* gamma  = (const float*)d_in[8];
    const float* beta   = (const float*)d_in[9];
    const float* mean   = (const float*)d_in[10];
    const float* var    = (const float*)d_in[11];
    const float* w_out  = (const float*)d_in[12];
    const float* b_out  = (const float*)d_in[13];
    float* out = (float*)d_out;
    char* ws = (char*)d_ws;

    // workspace layout (bytes)
    _Float16* x1t      = (_Float16*)(ws + 0);          // [32768][768] (phase 1)
    _Float16* x2t      = (_Float16*)(ws + 50331648);   // [32768][768] (phase 1)
    _Float16* x1p      = (_Float16*)(ws + 100663296);  // [32768][256]
    _Float16* x2p      = (_Float16*)(ws + 117440512);  // [32768][256]
    // phase 2 reuses the x1t region:
    _Float16* theta_t  = (_Float16*)(ws + 0);          // [32768][128]
    _Float16* phi_t    = (_Float16*)(ws + 8388608);    // [32768][128]
    _Float16* gbuf     = (_Float16*)(ws + 16777216);   // [128][32768]
    _Float16* y_t      = (_Float16*)(ws + 25165824);   // [32768][128]
    _Float16* w_conv_h = (_Float16*)(ws + 134217728);  // [256][768]
    _Float16* w_theta_h= (_Float16*)(ws + 134610944);  // [128][256]
    _Float16* w_phi_h  = (_Float16*)(ws + 134676480);  // [128][256]
    _Float16* w_g_h    = (_Float16*)(ws + 134742016);  // [128][256]
    _Float16* Acat     = (_Float16*)(ws + 134807552);  // [32][384]
    float*    c0       = (float*)   (ws + 134832128);  // [32]

    k_prep<<<64, 256, 0, stream>>>(w_conv, w_theta, w_phi, w_g, w_W, b_W,
                                   gamma, beta, mean, var, w_out, b_out,
                                   w_conv_h, w_theta_h, w_phi_h, w_g_h, Acat, c0);
    k_transpose<<<dim3(64, 12, 16), 256, 0, stream>>>(x1, x2, x1t, x2t);
    // conv: x1p_t[(b,n)][o] = sum_c x1t[(b,n)][c] * w_conv[o][c]
    k_gemm_nt<<<dim3(256, 2), 256, 0, stream>>>(x1t, w_conv_h, x1p, 768, 256);
    k_gemm_nt<<<dim3(256, 2), 256, 0, stream>>>(x2t, w_conv_h, x2p, 768, 256);
    // theta_t[(b,n)][i2] = sum_o x1p[(b,n)][o] * w_theta[i2][o]   (and phi from x2p)
    k_gemm_nt<<<dim3(256, 1), 256, 0, stream>>>(x1p, w_theta_h, theta_t, 256, 128);
    k_gemm_nt<<<dim3(256, 1), 256, 0, stream>>>(x2p, w_phi_h, phi_t, 256, 128);
    // g[c][(b,n)] = sum_o w_g[c][o] * x2p[(b,n)][o]
    k_gemm_nt<<<dim3(1, 256), 256, 0, stream>>>(w_g_h, x2p, gbuf, 256, 32768);
    k_attn<<<512, 256, 0, stream>>>(theta_t, phi_t, gbuf, y_t);
    k_out<<<256, 256, 0, stream>>>(y_t, x1p, Acat, c0, out);
    (void)in_sizes; (void)n_in; (void)out_size; (void)ws_size;
}

// Round 2
// 457.316 us; speedup vs baseline: 1.2923x; 1.2923x over previous
//
#include <hip/hip_runtime.h>

typedef _Float16 half8 __attribute__((ext_vector_type(8)));
typedef _Float16 half4v __attribute__((ext_vector_type(4)));
typedef float floatx4 __attribute__((ext_vector_type(4)));

#define MFMA16(a,b,c) __builtin_amdgcn_mfma_f32_16x16x32_f16((a),(b),(c),0,0,0)

// B=8, Cin=768, H=W=64, N=4096, NT=32768, MID=256, INTER=128, OUT=20

// ---------------------------------------------------------------------------
// Weight fp32->fp16 conversion
// ---------------------------------------------------------------------------
__global__ __launch_bounds__(256) void k_convert(
    const float* __restrict__ w_conv, const float* __restrict__ w_theta,
    const float* __restrict__ w_phi, const float* __restrict__ w_g,
    _Float16* __restrict__ w_conv_h, _Float16* __restrict__ w_theta_h,
    _Float16* __restrict__ w_phi_h, _Float16* __restrict__ w_g_h)
{
    int tid = blockIdx.x * 256 + threadIdx.x;
    int nth = gridDim.x * 256;
    for (int i = tid; i < 256 * 768; i += nth) w_conv_h[i] = (_Float16)w_conv[i];
    for (int i = tid; i < 128 * 256; i += nth) {
        w_theta_h[i] = (_Float16)w_theta[i];
        w_phi_h[i]   = (_Float16)w_phi[i];
        w_g_h[i]     = (_Float16)w_g[i];
    }
}

// ---------------------------------------------------------------------------
// Fold W->BN->out: Acat[32][384] fp16, c0[32] f32.  block = one u row.
// out[u][n] = sum_k Acat[u][k<128]*y[k][n] + sum_o Acat[u][128+o]*x1p[o][n] + c0[u]
// ---------------------------------------------------------------------------
__global__ __launch_bounds__(256) void k_fold(
    const float* __restrict__ w_W, const float* __restrict__ b_W,
    const float* __restrict__ gamma, const float* __restrict__ beta,
    const float* __restrict__ mean, const float* __restrict__ var,
    const float* __restrict__ w_out, const float* __restrict__ b_out,
    _Float16* __restrict__ Acat, float* __restrict__ c0)
{
    int u = blockIdx.x, t = threadIdx.x;
    __shared__ float woi[256];   // w_out[u][o] * inv[o]
    __shared__ float wcv[256];   // w_out[u][o] * (b_W*inv + beta - mean*inv)[o]
    if (u >= 20) {
        for (int k = t; k < 384; k += 256) Acat[u * 384 + k] = (_Float16)0.f;
        if (t == 0) c0[u] = 0.f;
        return;
    }
    {
        float inv = gamma[t] * rsqrtf(var[t] + 1e-5f);
        float wo = w_out[u * 256 + t];
        woi[t] = wo * inv;
        wcv[t] = wo * (b_W[t] * inv + beta[t] - mean[t] * inv);
    }
    __syncthreads();
    for (int k = t; k < 384; k += 256) {
        float v;
        if (k < 128) {
            v = 0.f;
            for (int o = 0; o < 256; ++o) v += woi[o] * w_W[o * 128 + k];
        } else {
            v = w_out[u * 256 + (k - 128)];
        }
        Acat[u * 384 + k] = (_Float16)v;
    }
    if (t == 0) {
        float s = b_out[u];
        for (int o = 0; o < 256; ++o) s += wcv[o];
        c0[u] = s;
    }
}

// ---------------------------------------------------------------------------
// Transpose + convert: x [b][768][4096] fp32 -> xt [(b*4096+n)][768] fp16
// LDS pad 65 (conflict-free: bank = (c+n+e) spread, 2-way max)
// ---------------------------------------------------------------------------
__global__ __launch_bounds__(256) void k_transpose(
    const float* __restrict__ x1, const float* __restrict__ x2,
    _Float16* __restrict__ x1t, _Float16* __restrict__ x2t)
{
    int z = blockIdx.z >> 3, b = blockIdx.z & 7;
    const float* X = (z ? x2 : x1) + (size_t)b * 768 * 4096;
    _Float16* XT = (z ? x2t : x1t) + (size_t)b * 4096 * 768;
    int n0 = blockIdx.x * 64, c0 = blockIdx.y * 64;
    __shared__ float tile[64][65];
    int t = threadIdx.x;
    {
        int c = t >> 2, ns = (t & 3) * 16;
        const float* src = X + (size_t)(c0 + c) * 4096 + n0 + ns;
#pragma unroll
        for (int e = 0; e < 4; ++e)
            *(float4*)&tile[c][ns + e * 4] = *(const float4*)(src + e * 4);
    }
    __syncthreads();
    {
        int n = t >> 2, cs = (t & 3) * 16;
        _Float16 outv[16];
#pragma unroll
        for (int e = 0; e < 16; ++e) outv[e] = (_Float16)tile[cs + e][n];
        _Float16* dst = XT + (size_t)(n0 + n) * 768 + c0 + cs;
        *(half8*)(dst)     = *(half8*)&outv[0];
        *(half8*)(dst + 8) = *(half8*)&outv[8];
    }
}

// ---------------------------------------------------------------------------
// NT GEMM: C[m][n] = sum_k A[m][k]*B[n][k], fp16, f32 acc. Tile 128x128 BK=32.
// perm!=0: permute stored column within 32-groups (for attention PV operand):
//   col = 32B+16h+4q+e  ->  32B+8q+4h+e
// ---------------------------------------------------------------------------
__global__ __launch_bounds__(256) void k_gemm_nt(
    const _Float16* __restrict__ A, const _Float16* __restrict__ B,
    _Float16* __restrict__ C, int K, int ldc, int perm)
{
    int m0 = blockIdx.x * 128, n0 = blockIdx.y * 128;
    __shared__ _Float16 As[128][72];
    __shared__ _Float16 Bs[128][72];
    int t = threadIdx.x, wave = t >> 6, lane = t & 63;
    int wm = (wave >> 1) * 64, wn = (wave & 1) * 64;
    int fl = lane & 15, fq = lane >> 4;
    int sr = t >> 2, sc = (t & 3) * 8;

    floatx4 acc[4][4];
#pragma unroll
    for (int i = 0; i < 4; ++i)
#pragma unroll
        for (int j = 0; j < 4; ++j) acc[i][j] = (floatx4){0.f, 0.f, 0.f, 0.f};

    for (int ko = 0; ko < K; ko += 32) {
        __syncthreads();
        half8 av0 = *(const half8*)(A + (size_t)(m0 + sr) * K + ko + sc);
        half8 av1 = *(const half8*)(A + (size_t)(m0 + sr + 64) * K + ko + sc);
        half8 bv0 = *(const half8*)(B + (size_t)(n0 + sr) * K + ko + sc);
        half8 bv1 = *(const half8*)(B + (size_t)(n0 + sr + 64) * K + ko + sc);
        *(half8*)&As[sr][sc] = av0;
        *(half8*)&As[sr + 64][sc] = av1;
        *(half8*)&Bs[sr][sc] = bv0;
        *(half8*)&Bs[sr + 64][sc] = bv1;
        __syncthreads();
        half8 af[4], bf[4];
#pragma unroll
        for (int i = 0; i < 4; ++i) af[i] = *(const half8*)&As[wm + 16 * i + fl][8 * fq];
#pragma unroll
        for (int j = 0; j < 4; ++j) bf[j] = *(const half8*)&Bs[wn + 16 * j + fl][8 * fq];
#pragma unroll
        for (int i = 0; i < 4; ++i)
#pragma unroll
            for (int j = 0; j < 4; ++j) acc[i][j] = MFMA16(af[i], bf[j], acc[i][j]);
    }
#pragma unroll
    for (int i = 0; i < 4; ++i)
#pragma unroll
        for (int j = 0; j < 4; ++j) {
            int row = m0 + wm + 16 * i + 4 * fq;
            int col = n0 + wn + 16 * j + fl;
            int cs2 = perm ? ((col & ~31) | (((col >> 2) & 3) << 3) |
                              (((col >> 4) & 1) << 2) | (col & 3))
                           : col;
#pragma unroll
            for (int r = 0; r < 4; ++r)
                C[(size_t)(row + r) * ldc + cs2] = (_Float16)acc[i][j][r];
        }
}

// ---------------------------------------------------------------------------
// Flash attention, S^T scheme. Block: 128 i-rows (4 waves x 32i), half of j.
// theta_t/phi_t: [(b*4096+n)][128] fp16; gbuf: [128][32768] fp16, PRE-PERMUTED
// along j within 32-groups. Outputs raw partials Opart (f32) + m,l per row.
// Per wave: Q resident (32 regs), P stays in registers (C-layout == B-operand
// under the gbuf permutation). LDS: only K and G staging, conflict-free pads.
// ---------------------------------------------------------------------------
__global__ __launch_bounds__(256, 2) void k_attn2(
    const _Float16* __restrict__ theta_t, const _Float16* __restrict__ phi_t,
    const _Float16* __restrict__ gbuf, float* __restrict__ Opart,
    float* __restrict__ Mp, float* __restrict__ Lp)
{
    int bi = blockIdx.x;
    int b = bi & 7;            // batch -> XCD affinity
    int r5 = bi >> 3;          // 0..63
    int iblk = r5 & 31, jh = r5 >> 5;
    int i0g = b * 4096 + iblk * 128;
    int t = threadIdx.x, wave = t >> 6, lane = t & 63;
    int fl = lane & 15, fq = lane >> 4;
    int iw = i0g + wave * 32;

    __shared__ _Float16 Ks[64][132];
    __shared__ _Float16 Gs[128][68];

    // Q resident: B-frag layout B[n=i][k=c], lane: n=fl, k=8*fq+e
    half8 qf[2][4];
#pragma unroll
    for (int it = 0; it < 2; ++it)
#pragma unroll
        for (int kc = 0; kc < 4; ++kc)
            qf[it][kc] = *(const half8*)(theta_t +
                (size_t)(iw + 16 * it + fl) * 128 + kc * 32 + 8 * fq);

    floatx4 O[8][2];
#pragma unroll
    for (int ct = 0; ct < 8; ++ct)
#pragma unroll
        for (int it = 0; it < 2; ++it) O[ct][it] = (floatx4){0.f, 0.f, 0.f, 0.f};
    float m[2] = {-1e30f, -1e30f}, l[2] = {0.f, 0.f};

    int jbase = b * 4096 + jh * 2048;
    for (int jc = 0; jc < 32; ++jc) {
        int j0g = jbase + jc * 64;
        __syncthreads();
        {   // stage K chunk [64 j][128 c], pad 132 (even bank coverage)
            int jr = t >> 2, cs = (t & 3) * 32;
            const _Float16* src = phi_t + (size_t)(j0g + jr) * 128 + cs;
#pragma unroll
            for (int e = 0; e < 4; ++e)
                *(half8*)&Ks[jr][cs + 8 * e] = *(const half8*)(src + 8 * e);
        }
        {   // stage G chunk [128 c][64 j] (already permuted in gbuf), pad 68
            int c = t >> 1, js = (t & 1) * 32;
            const _Float16* src = gbuf + (size_t)c * 32768 + j0g + js;
#pragma unroll
            for (int e = 0; e < 4; ++e)
                *(half8*)&Gs[c][js + 8 * e] = *(const half8*)(src + 8 * e);
        }
        __syncthreads();

        // S^T[j][i] = sum_c K[j][c] Q[i][c]; A=K frag (m=j), B=Q frag (n=i)
        floatx4 S[4][2];
#pragma unroll
        for (int jt = 0; jt < 4; ++jt)
#pragma unroll
            for (int it = 0; it < 2; ++it) S[jt][it] = (floatx4){0.f, 0.f, 0.f, 0.f};
#pragma unroll
        for (int kc = 0; kc < 4; ++kc)
#pragma unroll
            for (int jt = 0; jt < 4; ++jt) {
                half8 af = *(const half8*)&Ks[16 * jt + fl][kc * 32 + 8 * fq];
                S[jt][0] = MFMA16(af, qf[0][kc], S[jt][0]);
                S[jt][1] = MFMA16(af, qf[1][kc], S[jt][1]);
            }

        // online softmax: lane holds 16 j-values for ONE i per it (i = ...+fl)
        half8 pk[2][2];
        float alpha[2];
#pragma unroll
        for (int it = 0; it < 2; ++it) {
            float mx = S[0][it][0];
#pragma unroll
            for (int jt = 0; jt < 4; ++jt)
#pragma unroll
                for (int rr = 0; rr < 4; ++rr) mx = fmaxf(mx, S[jt][it][rr]);
            mx = fmaxf(mx, __shfl_xor(mx, 16, 64));
            mx = fmaxf(mx, __shfl_xor(mx, 32, 64));
            float mn = fmaxf(m[it], mx);
            alpha[it] = __expf(m[it] - mn);
            m[it] = mn;
            float sum = 0.f;
#pragma unroll
            for (int jt = 0; jt < 4; ++jt)
#pragma unroll
                for (int rr = 0; rr < 4; ++rr) {
                    float pv = __expf(S[jt][it][rr] - mn);
                    S[jt][it][rr] = pv;
                    sum += pv;
                }
            sum += __shfl_xor(sum, 16, 64);
            sum += __shfl_xor(sum, 32, 64);
            l[it] = l[it] * alpha[it] + sum;
            // pack P^T as PV B-operand: slot 8q+e: e<4 -> tile 2kj reg e,
            // e>=4 -> tile 2kj+1 reg e-4  (matches gbuf permutation)
#pragma unroll
            for (int kj = 0; kj < 2; ++kj)
#pragma unroll
                for (int e = 0; e < 8; ++e)
                    pk[it][kj][e] = (_Float16)S[2 * kj + (e >> 2)][it][e & 3];
        }
        // rescale O, then PV: O^T[c][i] += sum_j G[c][j] P^T[j][i]
#pragma unroll
        for (int ct = 0; ct < 8; ++ct)
#pragma unroll
            for (int it = 0; it < 2; ++it)
#pragma unroll
                for (int rr = 0; rr < 4; ++rr) O[ct][it][rr] *= alpha[it];
#pragma unroll
        for (int kj = 0; kj < 2; ++kj)
#pragma unroll
            for (int ct = 0; ct < 8; ++ct) {
                half8 gf = *(const half8*)&Gs[16 * ct + fl][kj * 32 + 8 * fq];
                O[ct][0] = MFMA16(gf, pk[0][kj], O[ct][0]);
                O[ct][1] = MFMA16(gf, pk[1][kj], O[ct][1]);
            }
    }

    // raw partials: Opart[jh][i][c] f32 (float4: 4 consecutive c = 4fq+r)
#pragma unroll
    for (int it = 0; it < 2; ++it) {
        size_t ig = (size_t)jh * 32768 + iw + 16 * it + fl;
#pragma unroll
        for (int ct = 0; ct < 8; ++ct)
            *(floatx4*)&Opart[ig * 128 + 16 * ct + 4 * fq] = O[ct][it];
        if (fq == 0) { Mp[ig] = m[it]; Lp[ig] = l[it]; }
    }
}

// ---------------------------------------------------------------------------
// Merge the two j-half partials -> y_t [(b*4096+i)][128] fp16
// ---------------------------------------------------------------------------
__global__ __launch_bounds__(256) void k_merge(
    const float* __restrict__ Opart, const float* __restrict__ Mp,
    const float* __restrict__ Lp, _Float16* __restrict__ y_t)
{
    int g = blockIdx.x * 256 + threadIdx.x;
    int i = g >> 5, cb = (g & 31) * 4;
    float m0 = Mp[i], m1 = Mp[32768 + i];
    float l0 = Lp[i], l1 = Lp[32768 + i];
    float M = fmaxf(m0, m1);
    float w0 = __expf(m0 - M), w1 = __expf(m1 - M);
    float inv = 1.f / (w0 * l0 + w1 * l1);
    w0 *= inv; w1 *= inv;
    float4 o0 = *(const float4*)&Opart[(size_t)i * 128 + cb];
    float4 o1 = *(const float4*)&Opart[(size_t)(32768 + i) * 128 + cb];
    half4v y;
    y[0] = (_Float16)(w0 * o0.x + w1 * o1.x);
    y[1] = (_Float16)(w0 * o0.y + w1 * o1.y);
    y[2] = (_Float16)(w0 * o0.z + w1 * o1.z);
    y[3] = (_Float16)(w0 * o0.w + w1 * o1.w);
    *(half4v*)&y_t[(size_t)i * 128 + cb] = y;
}

// ---------------------------------------------------------------------------
// Epilogue GEMM: out[u][ng] = sum_k Acat[u][k]*concat(y_t,x1p)[ng][k] + c0[u]
// ---------------------------------------------------------------------------
__global__ __launch_bounds__(256) void k_out(
    const _Float16* __restrict__ y_t, const _Float16* __restrict__ x1p_t,
    const _Float16* __restrict__ Acat, const float* __restrict__ c0,
    float* __restrict__ out)
{
    int n0 = blockIdx.x * 128;
    __shared__ _Float16 As[32][72];
    __shared__ _Float16 Bs[128][72];
    __shared__ float c0s[32];
    int t = threadIdx.x, wave = t >> 6, lane = t & 63;
    int fl = lane & 15, fq = lane >> 4;
    int wn = wave * 32;
    if (t < 32) c0s[t] = c0[t];

    floatx4 acc[2][2];
#pragma unroll
    for (int i = 0; i < 2; ++i)
#pragma unroll
        for (int j = 0; j < 2; ++j) acc[i][j] = (floatx4){0.f, 0.f, 0.f, 0.f};

    for (int ko = 0; ko < 12; ++ko) {
        int kg = ko * 32;
        __syncthreads();
        {
            int n = t >> 1, ks = (t & 1) * 16;
            const _Float16* src = (kg < 128)
                ? y_t + (size_t)(n0 + n) * 128 + kg + ks
                : x1p_t + (size_t)(n0 + n) * 256 + (kg - 128) + ks;
            *(half8*)&Bs[n][ks]     = *(const half8*)src;
            *(half8*)&Bs[n][ks + 8] = *(const half8*)(src + 8);
        }
        if (t < 128) {
            int mm = t >> 2, ks = (t & 3) * 8;
            *(half8*)&As[mm][ks] = *(const half8*)(Acat + mm * 384 + kg + ks);
        }
        __syncthreads();
        half8 af[2], bf[2];
#pragma unroll
        for (int mt = 0; mt < 2; ++mt) af[mt] = *(const half8*)&As[16 * mt + fl][8 * fq];
#pragma unroll
        for (int nt = 0; nt < 2; ++nt) bf[nt] = *(const half8*)&Bs[wn + 16 * nt + fl][8 * fq];
#pragma unroll
        for (int mt = 0; mt < 2; ++mt)
#pragma unroll
            for (int nt = 0; nt < 2; ++nt) acc[mt][nt] = MFMA16(af[mt], bf[nt], acc[mt][nt]);
    }
#pragma unroll
    for (int mt = 0; mt < 2; ++mt)
#pragma unroll
        for (int nt = 0; nt < 2; ++nt)
#pragma unroll
            for (int r = 0; r < 4; ++r) {
                int u = 16 * mt + 4 * fq + r;
                if (u < 20) {
                    int ng = n0 + wn + 16 * nt + fl;
                    int b = ng >> 12, n = ng & 4095;
                    out[((size_t)b * 20 + u) * 4096 + n] = acc[mt][nt][r] + c0s[u];
                }
            }
}

// ---------------------------------------------------------------------------
extern "C" void kernel_launch(void* const* d_in, const int* in_sizes, int n_in,
                              void* d_out, int out_size, void* d_ws, size_t ws_size,
                              hipStream_t stream)
{
    const float* x1     = (const float*)d_in[0];
    const float* x2     = (const float*)d_in[1];
    const float* w_conv = (const float*)d_in[2];
    const float* w_theta= (const float*)d_in[3];
    const float* w_phi  = (const float*)d_in[4];
    const float* w_g    = (const float*)d_in[5];
    const float* w_W    = (const float*)d_in[6];
    const float* b_W    = (const float*)d_in[7];
    const float* gamma  = (const float*)d_in[8];
    const float* beta   = (const float*)d_in[9];
    const float* mean   = (const float*)d_in[10];
    const float* var    = (const float*)d_in[11];
    const float* w_out  = (const float*)d_in[12];
    const float* b_out  = (const float*)d_in[13];
    float* out = (float*)d_out;
    char* ws = (char*)d_ws;

    // workspace layout (bytes)
    _Float16* x1t      = (_Float16*)(ws + 0);          // [32768][768] (phase 1)
    _Float16* x2t      = (_Float16*)(ws + 50331648);   // [32768][768] (phase 1)
    _Float16* x1p      = (_Float16*)(ws + 100663296);  // [32768][256]
    _Float16* x2p      = (_Float16*)(ws + 117440512);  // [32768][256]
    // phase 2 (reuses x1t/x2t region):
    _Float16* theta_t  = (_Float16*)(ws + 0);          // [32768][128]
    _Float16* phi_t    = (_Float16*)(ws + 8388608);    // [32768][128]
    _Float16* gbuf     = (_Float16*)(ws + 16777216);   // [128][32768] permuted
    _Float16* y_t      = (_Float16*)(ws + 25165824);   // [32768][128]
    float*    Opart    = (float*)   (ws + 33554432);   // [2][32768][128] f32
    float*    Mp       = (float*)   (ws + 67108864);   // [2][32768]
    float*    Lp       = (float*)   (ws + 67371008);   // [2][32768]
    _Float16* w_conv_h = (_Float16*)(ws + 134217728);  // [256][768]
    _Float16* w_theta_h= (_Float16*)(ws + 134610944);  // [128][256]
    _Float16* w_phi_h  = (_Float16*)(ws + 134676480);  // [128][256]
    _Float16* w_g_h    = (_Float16*)(ws + 134742016);  // [128][256]
    _Float16* Acat     = (_Float16*)(ws + 134807552);  // [32][384]
    float*    c0       = (float*)   (ws + 134832128);  // [32]

    k_convert<<<64, 256, 0, stream>>>(w_conv, w_theta, w_phi, w_g,
                                      w_conv_h, w_theta_h, w_phi_h, w_g_h);
    k_fold<<<32, 256, 0, stream>>>(w_W, b_W, gamma, beta, mean, var,
                                   w_out, b_out, Acat, c0);
    k_transpose<<<dim3(64, 12, 16), 256, 0, stream>>>(x1, x2, x1t, x2t);
    k_gemm_nt<<<dim3(256, 2), 256, 0, stream>>>(x1t, w_conv_h, x1p, 768, 256, 0);
    k_gemm_nt<<<dim3(256, 2), 256, 0, stream>>>(x2t, w_conv_h, x2p, 768, 256, 0);
    k_gemm_nt<<<dim3(256, 1), 256, 0, stream>>>(x1p, w_theta_h, theta_t, 256, 128, 0);
    k_gemm_nt<<<dim3(256, 1), 256, 0, stream>>>(x2p, w_phi_h, phi_t, 256, 128, 0);
    k_gemm_nt<<<dim3(1, 256), 256, 0, stream>>>(w_g_h, x2p, gbuf, 256, 32768, 1);
    k_attn2<<<512, 256, 0, stream>>>(theta_t, phi_t, gbuf, Opart, Mp, Lp);
    k_merge<<<4096, 256, 0, stream>>>(Opart, Mp, Lp, y_t);
    k_out<<<256, 256, 0, stream>>>(y_t, x1p, Acat, c0, out);
    (void)in_sizes; (void)n_in; (void)out_size; (void)ws_size;
}